// Round 11
// baseline (96.955 us; speedup 1.0000x reference)
//
#include <hip/hip_runtime.h>

#define NG 512
#define NF 32
#define NP (96 * 96 * 16)   // 147456 points
#define TPB 256             // 4 waves; 64 points per block, 4 gaussian segments
#define PTS 64
#define NSEG 4
#define CPS 4               // chunks (of 32 gaussians) per segment

typedef _Float16 half8 __attribute__((ext_vector_type(8)));
typedef __fp16  fp16x2 __attribute__((ext_vector_type(2)));
typedef float f32x4 __attribute__((ext_vector_type(4)));
typedef unsigned uint4v __attribute__((ext_vector_type(4)));
typedef unsigned uint2v __attribute__((ext_vector_type(2)));

union H2U { fp16x2 h; unsigned u; };
union FRAG { unsigned u[4]; uint4v v; half8 h; };

__device__ __forceinline__ unsigned packh(__fp16 a, __fp16 b) {
    H2U p; p.h = (fp16x2){a, b}; return p.u;
}
__device__ __forceinline__ unsigned pkrtz(float a, float b) {
    H2U p; p.h = __builtin_amdgcn_cvt_pkrtz(a, b); return p.u;
}
// Swizzled dword index into a [256 rows][16 dw] LDS image (bank-balanced,
// 16B-aligned) — R7..R10-verified.
__device__ __forceinline__ int ridx(int row, int grp) {
    return row * 16 + 4 * (grp ^ (row & 3));
}

// ---------------------------------------------------------------------------
// gr_pack (R7+-verified, unchanged): blocks 0-1 psi A-frag image (hi/lo f16
// split, MFMA A-operand order); blocks 2-33 feats B-frag image.
// ---------------------------------------------------------------------------
__global__ __launch_bounds__(256) void gr_pack(
    const float* __restrict__ means,
    const float* __restrict__ scales,
    const float* __restrict__ rots,
    const float* __restrict__ opac,
    const float* __restrict__ cam,
    const float* __restrict__ feats,
    unsigned* __restrict__ psi,
    unsigned* __restrict__ ftg)
{
    const int b = blockIdx.x;
    const int tid = threadIdx.x;

    if (b < 2) {
        const int n = b * 256 + tid;   // 0..511

        float mx = means[n * 3 + 0];
        float my = means[n * 3 + 1];
        float mz = means[n * 3 + 2];

        float h0 = cam[0]  * mx + cam[1]  * my + cam[2]  * mz + cam[3];
        float h1 = cam[4]  * mx + cam[5]  * my + cam[6]  * mz + cam[7];
        float h2 = cam[8]  * mx + cam[9]  * my + cam[10] * mz + cam[11];
        float h3 = cam[12] * mx + cam[13] * my + cam[14] * mz + cam[15];
        float ih3 = 1.0f / h3;
        mx = h0 * ih3; my = h1 * ih3; mz = h2 * ih3;

        float qw = rots[n * 4 + 0];
        float qx = rots[n * 4 + 1];
        float qy = rots[n * 4 + 2];
        float qz = rots[n * 4 + 3];
        float qinv = 1.0f / sqrtf(qw * qw + qx * qx + qy * qy + qz * qz);
        qw *= qinv; qx *= qinv; qy *= qinv; qz *= qinv;

        float R00 = 1.0f - 2.0f * (qy * qy + qz * qz);
        float R01 = 2.0f * (qx * qy - qw * qz);
        float R02 = 2.0f * (qx * qz + qw * qy);
        float R10 = 2.0f * (qx * qy + qw * qz);
        float R11 = 1.0f - 2.0f * (qx * qx + qz * qz);
        float R12 = 2.0f * (qy * qz - qw * qx);
        float R20 = 2.0f * (qx * qz - qw * qy);
        float R21 = 2.0f * (qy * qz + qw * qx);
        float R22 = 1.0f - 2.0f * (qx * qx + qy * qy);

        float s0 = scales[n * 3 + 0];
        float s1 = scales[n * 3 + 1];
        float s2 = scales[n * 3 + 2];
        const float es = 0.7213475204444817f;   // 0.5*log2(e)
        float i0 = es / (s0 * s0);
        float i1 = es / (s1 * s1);
        float i2 = es / (s2 * s2);

        float a00 = R00 * R00 * i0 + R01 * R01 * i1 + R02 * R02 * i2;
        float a01 = R00 * R10 * i0 + R01 * R11 * i1 + R02 * R12 * i2;
        float a02 = R00 * R20 * i0 + R01 * R21 * i1 + R02 * R22 * i2;
        float a11 = R10 * R10 * i0 + R11 * R11 * i1 + R12 * R12 * i2;
        float a12 = R10 * R20 * i0 + R11 * R21 * i1 + R12 * R22 * i2;
        float a22 = R20 * R20 * i0 + R21 * R21 * i1 + R22 * R22 * i2;

        float amx = a00 * mx + a01 * my + a02 * mz;
        float amy = a01 * mx + a11 * my + a12 * mz;
        float amz = a02 * mx + a12 * my + a22 * mz;

        float psv[10];
        psv[0] = -a00; psv[1] = -a11; psv[2] = -a22;
        psv[3] = -2.0f * a01; psv[4] = -2.0f * a02; psv[5] = -2.0f * a12;
        psv[6] = 2.0f * amx; psv[7] = 2.0f * amy; psv[8] = 2.0f * amz;
        psv[9] = __log2f(opac[n]) - (mx * amx + my * amy + mz * amz);

        __fp16 s[32];
#pragma unroll
        for (int i = 0; i < 10; ++i) {
            __fp16 hi = (__fp16)psv[i];
            __fp16 lo = (__fp16)(psv[i] - (float)hi);
            s[i] = hi; s[10 + i] = lo; s[20 + i] = hi;
        }
        s[30] = (__fp16)0.f; s[31] = (__fp16)0.f;

        unsigned* base = psi + (n >> 4) * 256;
        const int lr = n & 15;
#pragma unroll
        for (int q = 0; q < 4; ++q)
#pragma unroll
            for (int jp = 0; jp < 4; ++jp)
                base[(lr + 16 * q) * 4 + jp] = packh(s[8 * q + 2 * jp], s[8 * q + 2 * jp + 1]);
    } else {
        int d = (b - 2) * 256 + tid;   // 0..8191
        int c  = d >> 9;
        int r  = d & 511;
        int nt = r >> 8;
        int l  = (r >> 2) & 63;
        int jp = r & 3;
        int n  = nt * 16 + (l & 15);
        int k0 = c * 32 + (l >> 4) * 8 + 2 * jp;
        ftg[d] = pkrtz(feats[k0 * NF + n], feats[(k0 + 1) * NF + n]);
    }
}

// ---------------------------------------------------------------------------
// gr_render: 64 points/block, 4 waves = 4 gaussian segments of 128.
// R11: depth-2 software pipeline over chunks with a double-buffered work
// image — stage A(c+1) (Q-GEMM + exp2 + alpha-write) fills the previously
// exposed alpha write->read round-trip of stage B(c) (T-chain + w + PV).
// All main-loop LDS is wave-private; in-order wave LDS makes it race-free.
// ---------------------------------------------------------------------------
__global__ __launch_bounds__(256, 4) void gr_render(
    const unsigned* __restrict__ psi,
    const unsigned* __restrict__ ftg,
    const float* __restrict__ coords,
    float* __restrict__ out)
{
    __shared__ uint4v shbuf[2 * 1024];       // 2 x 16 KB work images
    __shared__ float tT[NSEG][PTS];          // 1 KB: segment transmittances
    unsigned* const sh0 = (unsigned*)shbuf;
    unsigned* const sh1 = sh0 + 4096;

    const int tid  = threadIdx.x;
    const int ln   = tid & 15;
    const int quad = (tid >> 4) & 3;
    const int wv   = tid >> 6;
    const int lane = tid & 63;

    const int p = blockIdx.x * PTS + lane;   // this lane's point
    const float cx = coords[p * 3 + 0];
    const float cy = coords[p * 3 + 1];
    const float cz = coords[p * 3 + 2];

    // ---- phi' (hi/lo split) -> own wave's rows of img0 -> B-frags
    {
        float ph[10] = {cx * cx, cy * cy, cz * cz, cx * cy, cx * cz, cy * cz,
                        cx, cy, cz, 1.0f};
        __fp16 s[32];
#pragma unroll
        for (int i = 0; i < 10; ++i) {
            __fp16 hi = (__fp16)ph[i];
            __fp16 lo = (__fp16)(ph[i] - (float)hi);
            s[i] = hi; s[10 + i] = hi; s[20 + i] = lo;
        }
        s[30] = (__fp16)0.f; s[31] = (__fp16)0.f;
#pragma unroll
        for (int i = 0; i < 4; ++i) {
            uint4v v = (uint4v){packh(s[8 * i + 0], s[8 * i + 1]),
                                packh(s[8 * i + 2], s[8 * i + 3]),
                                packh(s[8 * i + 4], s[8 * i + 5]),
                                packh(s[8 * i + 6], s[8 * i + 7])};
            *(uint4v*)&sh0[ridx(tid, i)] = v;
        }
    }

    FRAG phif[4];
#pragma unroll
    for (int nt = 0; nt < 4; ++nt)
        phif[nt].v = *(const uint4v*)&sh0[ridx(wv * 64 + nt * 16 + ln, quad)];

    f32x4 pvacc[4][2];
#pragma unroll
    for (int mt = 0; mt < 4; ++mt) {
        pvacc[mt][0] = (f32x4){0.f, 0.f, 0.f, 0.f};
        pvacc[mt][1] = (f32x4){0.f, 0.f, 0.f, 0.f};
    }
    float T = 1.0f;
    const int cbase = wv * CPS;

    // ---- stage A: pa loads + Q-GEMM + exp2 -> alpha-write into img
    auto stageA = [&](int c, unsigned* img) {
        FRAG pa0, pa1;
        pa0.v = ((const uint4v*)(psi + (2 * c + 0) * 256))[lane];
        pa1.v = ((const uint4v*)(psi + (2 * c + 1) * 256))[lane];
#pragma unroll
        for (int m = 0; m < 2; ++m) {
            const FRAG& pa = m ? pa1 : pa0;
            f32x4 qa[4];
#pragma unroll
            for (int nt = 0; nt < 4; ++nt)
                qa[nt] = __builtin_amdgcn_mfma_f32_16x16x32_f16(
                    pa.h, phif[nt].h, (f32x4){0.f, 0.f, 0.f, 0.f}, 0, 0, 0);
#pragma unroll
            for (int nt = 0; nt < 4; ++nt) {
                float a0 = __builtin_amdgcn_exp2f(qa[nt][0]);
                float a1 = __builtin_amdgcn_exp2f(qa[nt][1]);
                float a2 = __builtin_amdgcn_exp2f(qa[nt][2]);
                float a3 = __builtin_amdgcn_exp2f(qa[nt][3]);
                const int row = wv * 64 + nt * 16 + ln;
                const int dbase = row * 16 + ((m * 8 + quad * 2) ^ (4 * (row & 3)));
                *(uint2v*)&img[dbase] = (uint2v){pkrtz(a0, a1), pkrtz(a2, a3)};
            }
        }
    };

    // ---- stage B: bf loads + T-chain (quad-factored, R10-verified) + w-write
    //      + A-frag read + PV-GEMM, all on img
    auto stageB = [&](int c, unsigned* img) {
        FRAG bf0, bf1;
        bf0.v = ((const uint4v*)(ftg + c * 512 + 0))[lane];
        bf1.v = ((const uint4v*)(ftg + c * 512 + 256))[lane];

#pragma unroll
        for (int i = 0; i < 4; ++i) {
            uint4v a4 = *(const uint4v*)&img[ridx(tid, i)];
            uint4v w4;
#pragma unroll
            for (int h = 0; h < 2; ++h) {
                H2U u0; u0.u = a4[2 * h + 0];
                H2U u1; u1.u = a4[2 * h + 1];
                float a0 = (float)u0.h[0];
                float a1 = (float)u0.h[1];
                float a2 = (float)u1.h[0];
                float a3 = (float)u1.h[1];
                float c1 = 1.0f - a0;
                float t1 = c1 * a1; float c2 = c1 - t1;
                float t2 = c2 * a2; float c3 = c2 - t2;
                float t3 = c3 * a3; float pq = c3 - t3;
                float w0 = T * a0;
                float w1 = T * t1;
                float w2 = T * t2;
                float w3 = T * t3;
                T = T * pq;
                w4[2 * h + 0] = pkrtz(w0, w1);
                w4[2 * h + 1] = pkrtz(w2, w3);
            }
            *(uint4v*)&img[ridx(tid, i)] = w4;
        }

#pragma unroll
        for (int mt = 0; mt < 4; ++mt) {
            FRAG af;
            af.v = *(const uint4v*)&img[ridx(wv * 64 + mt * 16 + ln, quad)];
            pvacc[mt][0] = __builtin_amdgcn_mfma_f32_16x16x32_f16(af.h, bf0.h, pvacc[mt][0], 0, 0, 0);
            pvacc[mt][1] = __builtin_amdgcn_mfma_f32_16x16x32_f16(af.h, bf1.h, pvacc[mt][1], 0, 0, 0);
        }
    };

    // ---- depth-2 pipeline: A0; A1|B0; A2|B1; A3|B2; B3
    stageA(cbase + 0, sh0);
    stageA(cbase + 1, sh1);  stageB(cbase + 0, sh0);
    stageA(cbase + 2, sh0);  stageB(cbase + 1, sh1);
    stageA(cbase + 3, sh1);  stageB(cbase + 2, sh0);
    stageB(cbase + 3, sh1);

    // ---- write segment partials (f16 feature-pairs) into img0 rows; dword d
    // of row p holds features (d, d+16). |acc| <= max|feat| since sum(w)<=1.
    tT[wv][lane] = T;
#pragma unroll
    for (int mt = 0; mt < 4; ++mt)
#pragma unroll
        for (int r = 0; r < 4; ++r)
            sh0[(wv * 64 + mt * 16 + quad * 4 + r) * 16 + ln] =
                pkrtz(pvacc[mt][0][r], pvacc[mt][1][r]);

    __syncthreads();

    // ---- compose segments: out = sum_s (prod_{s'<s} T_s') * acc_s
    {
        const int pp = tid >> 2;        // point 0..63
        const int g  = tid & 3;         // dword group (4 dwords)
        float t0 = tT[0][pp], t1 = tT[1][pp], t2 = tT[2][pp];
        float w1 = t0, w2 = t0 * t1, w3 = w2 * t2;

        float o[8];
        uint4v v0 = *(const uint4v*)&sh0[(0 * 64 + pp) * 16 + g * 4];
#pragma unroll
        for (int j = 0; j < 4; ++j) {
            H2U u; u.u = v0[j];
            o[j] = (float)u.h[0]; o[4 + j] = (float)u.h[1];
        }
        uint4v v1 = *(const uint4v*)&sh0[(1 * 64 + pp) * 16 + g * 4];
#pragma unroll
        for (int j = 0; j < 4; ++j) {
            H2U u; u.u = v1[j];
            o[j] = fmaf(w1, (float)u.h[0], o[j]);
            o[4 + j] = fmaf(w1, (float)u.h[1], o[4 + j]);
        }
        uint4v v2 = *(const uint4v*)&sh0[(2 * 64 + pp) * 16 + g * 4];
#pragma unroll
        for (int j = 0; j < 4; ++j) {
            H2U u; u.u = v2[j];
            o[j] = fmaf(w2, (float)u.h[0], o[j]);
            o[4 + j] = fmaf(w2, (float)u.h[1], o[4 + j]);
        }
        uint4v v3 = *(const uint4v*)&sh0[(3 * 64 + pp) * 16 + g * 4];
#pragma unroll
        for (int j = 0; j < 4; ++j) {
            H2U u; u.u = v3[j];
            o[j] = fmaf(w3, (float)u.h[0], o[j]);
            o[4 + j] = fmaf(w3, (float)u.h[1], o[4 + j]);
        }

        float* __restrict__ ob = out + (blockIdx.x * PTS + pp) * NF + g * 4;
        *(float4*)ob        = make_float4(o[0], o[1], o[2], o[3]);
        *(float4*)(ob + 16) = make_float4(o[4], o[5], o[6], o[7]);
    }
}

extern "C" void kernel_launch(void* const* d_in, const int* in_sizes, int n_in,
                              void* d_out, int out_size, void* d_ws, size_t ws_size,
                              hipStream_t stream)
{
    const float* means  = (const float*)d_in[0];   // (512,3)
    const float* scales = (const float*)d_in[1];   // (512,3)
    const float* rots   = (const float*)d_in[2];   // (512,4)
    const float* opac   = (const float*)d_in[3];   // (512,1)
    const float* feats  = (const float*)d_in[4];   // (512,32)
    const float* cam    = (const float*)d_in[5];   // (4,4)
    const float* coords = (const float*)d_in[6];   // (96,96,16,3)
    float* out = (float*)d_out;                    // (96,96,16,32) fp32

    unsigned* psi = (unsigned*)d_ws;               // 32 KiB: gaussian A-frag image
    unsigned* ftg = psi + 32 * 256;                // 32 KiB: feats B-frag image

    gr_pack<<<34, 256, 0, stream>>>(means, scales, rots, opac, cam, feats, psi, ftg);
    gr_render<<<NP / PTS, TPB, 0, stream>>>(psi, ftg, coords, out);
}

// Round 12
// 95.312 us; speedup vs baseline: 1.0172x; 1.0172x over previous
//
#include <hip/hip_runtime.h>

#define NG 512
#define NF 32
#define NP (96 * 96 * 16)   // 147456 points
#define TPB 256             // 4 waves; 64 points per block, 4 gaussian segments
#define PTS 64
#define NSEG 4
#define CPS 4               // chunks (of 32 gaussians) per segment

typedef _Float16 half8 __attribute__((ext_vector_type(8)));
typedef __fp16  fp16x2 __attribute__((ext_vector_type(2)));
typedef float f32x4 __attribute__((ext_vector_type(4)));
typedef unsigned uint4v __attribute__((ext_vector_type(4)));
typedef unsigned uint2v __attribute__((ext_vector_type(2)));

union H2U { fp16x2 h; unsigned u; };
union FRAG { unsigned u[4]; uint4v v; half8 h; };

__device__ __forceinline__ unsigned packh(__fp16 a, __fp16 b) {
    H2U p; p.h = (fp16x2){a, b}; return p.u;
}
__device__ __forceinline__ unsigned pkrtz(float a, float b) {
    H2U p; p.h = __builtin_amdgcn_cvt_pkrtz(a, b); return p.u;
}
// Swizzled dword index into a [256 rows][16 dw] LDS image (bank-balanced,
// 16B-aligned) — R7..R10-verified.
__device__ __forceinline__ int ridx(int row, int grp) {
    return row * 16 + 4 * (grp ^ (row & 3));
}

// ---------------------------------------------------------------------------
// gr_pack (R7+-verified): blocks 0-1 psi A-frag image (hi/lo f16 split,
// MFMA A-operand order); blocks 2-33 feats B-frag image.
// ---------------------------------------------------------------------------
__global__ __launch_bounds__(256) void gr_pack(
    const float* __restrict__ means,
    const float* __restrict__ scales,
    const float* __restrict__ rots,
    const float* __restrict__ opac,
    const float* __restrict__ cam,
    const float* __restrict__ feats,
    unsigned* __restrict__ psi,
    unsigned* __restrict__ ftg)
{
    const int b = blockIdx.x;
    const int tid = threadIdx.x;

    if (b < 2) {
        const int n = b * 256 + tid;   // 0..511

        float mx = means[n * 3 + 0];
        float my = means[n * 3 + 1];
        float mz = means[n * 3 + 2];

        float h0 = cam[0]  * mx + cam[1]  * my + cam[2]  * mz + cam[3];
        float h1 = cam[4]  * mx + cam[5]  * my + cam[6]  * mz + cam[7];
        float h2 = cam[8]  * mx + cam[9]  * my + cam[10] * mz + cam[11];
        float h3 = cam[12] * mx + cam[13] * my + cam[14] * mz + cam[15];
        float ih3 = 1.0f / h3;
        mx = h0 * ih3; my = h1 * ih3; mz = h2 * ih3;

        float qw = rots[n * 4 + 0];
        float qx = rots[n * 4 + 1];
        float qy = rots[n * 4 + 2];
        float qz = rots[n * 4 + 3];
        float qinv = 1.0f / sqrtf(qw * qw + qx * qx + qy * qy + qz * qz);
        qw *= qinv; qx *= qinv; qy *= qinv; qz *= qinv;

        float R00 = 1.0f - 2.0f * (qy * qy + qz * qz);
        float R01 = 2.0f * (qx * qy - qw * qz);
        float R02 = 2.0f * (qx * qz + qw * qy);
        float R10 = 2.0f * (qx * qy + qw * qz);
        float R11 = 1.0f - 2.0f * (qx * qx + qz * qz);
        float R12 = 2.0f * (qy * qz - qw * qx);
        float R20 = 2.0f * (qx * qz - qw * qy);
        float R21 = 2.0f * (qy * qz + qw * qx);
        float R22 = 1.0f - 2.0f * (qx * qx + qy * qy);

        float s0 = scales[n * 3 + 0];
        float s1 = scales[n * 3 + 1];
        float s2 = scales[n * 3 + 2];
        const float es = 0.7213475204444817f;   // 0.5*log2(e)
        float i0 = es / (s0 * s0);
        float i1 = es / (s1 * s1);
        float i2 = es / (s2 * s2);

        float a00 = R00 * R00 * i0 + R01 * R01 * i1 + R02 * R02 * i2;
        float a01 = R00 * R10 * i0 + R01 * R11 * i1 + R02 * R12 * i2;
        float a02 = R00 * R20 * i0 + R01 * R21 * i1 + R02 * R22 * i2;
        float a11 = R10 * R10 * i0 + R11 * R11 * i1 + R12 * R12 * i2;
        float a12 = R10 * R20 * i0 + R11 * R21 * i1 + R12 * R22 * i2;
        float a22 = R20 * R20 * i0 + R21 * R21 * i1 + R22 * R22 * i2;

        float amx = a00 * mx + a01 * my + a02 * mz;
        float amy = a01 * mx + a11 * my + a12 * mz;
        float amz = a02 * mx + a12 * my + a22 * mz;

        float psv[10];
        psv[0] = -a00; psv[1] = -a11; psv[2] = -a22;
        psv[3] = -2.0f * a01; psv[4] = -2.0f * a02; psv[5] = -2.0f * a12;
        psv[6] = 2.0f * amx; psv[7] = 2.0f * amy; psv[8] = 2.0f * amz;
        psv[9] = __log2f(opac[n]) - (mx * amx + my * amy + mz * amz);

        __fp16 s[32];
#pragma unroll
        for (int i = 0; i < 10; ++i) {
            __fp16 hi = (__fp16)psv[i];
            __fp16 lo = (__fp16)(psv[i] - (float)hi);
            s[i] = hi; s[10 + i] = lo; s[20 + i] = hi;
        }
        s[30] = (__fp16)0.f; s[31] = (__fp16)0.f;

        unsigned* base = psi + (n >> 4) * 256;
        const int lr = n & 15;
#pragma unroll
        for (int q = 0; q < 4; ++q)
#pragma unroll
            for (int jp = 0; jp < 4; ++jp)
                base[(lr + 16 * q) * 4 + jp] = packh(s[8 * q + 2 * jp], s[8 * q + 2 * jp + 1]);
    } else {
        int d = (b - 2) * 256 + tid;   // 0..8191
        int c  = d >> 9;
        int r  = d & 511;
        int nt = r >> 8;
        int l  = (r >> 2) & 63;
        int jp = r & 3;
        int n  = nt * 16 + (l & 15);
        int k0 = c * 32 + (l >> 4) * 8 + 2 * jp;
        ftg[d] = pkrtz(feats[k0 * NF + n], feats[(k0 + 1) * NF + n]);
    }
}

// ---------------------------------------------------------------------------
// gr_render (R10 configuration — session best, 94.9 us):
// 64 points/block, 4 waves = 4 gaussian segments of 128; single 16 KB work
// image; quad-factored T-chain (critical path 1 mul per 4 gaussians); all 4
// VMEM frag loads hoisted to chunk top (one vmcnt window).
// R11's depth-2 pipeline (33 KB LDS) regressed — do not reintroduce.
// ---------------------------------------------------------------------------
__global__ __launch_bounds__(256, 5) void gr_render(
    const unsigned* __restrict__ psi,
    const unsigned* __restrict__ ftg,
    const float* __restrict__ coords,
    float* __restrict__ out)
{
    __shared__ uint4v sh4[TPB * 4];          // 16 KB: [256 rows][16 dw]
    __shared__ float tT[NSEG][PTS];          // 1 KB: segment transmittances
    unsigned* sh = (unsigned*)sh4;

    const int tid  = threadIdx.x;
    const int ln   = tid & 15;
    const int quad = (tid >> 4) & 3;
    const int wv   = tid >> 6;
    const int lane = tid & 63;

    const int p = blockIdx.x * PTS + lane;   // this lane's point
    const float cx = coords[p * 3 + 0];
    const float cy = coords[p * 3 + 1];
    const float cz = coords[p * 3 + 2];

    // ---- phi' (hi/lo split) -> own wave's LDS rows -> B-frags (R7-verified)
    {
        float ph[10] = {cx * cx, cy * cy, cz * cz, cx * cy, cx * cz, cy * cz,
                        cx, cy, cz, 1.0f};
        __fp16 s[32];
#pragma unroll
        for (int i = 0; i < 10; ++i) {
            __fp16 hi = (__fp16)ph[i];
            __fp16 lo = (__fp16)(ph[i] - (float)hi);
            s[i] = hi; s[10 + i] = hi; s[20 + i] = lo;
        }
        s[30] = (__fp16)0.f; s[31] = (__fp16)0.f;
#pragma unroll
        for (int i = 0; i < 4; ++i) {
            uint4v v = (uint4v){packh(s[8 * i + 0], s[8 * i + 1]),
                                packh(s[8 * i + 2], s[8 * i + 3]),
                                packh(s[8 * i + 4], s[8 * i + 5]),
                                packh(s[8 * i + 6], s[8 * i + 7])};
            *(uint4v*)&sh[ridx(tid, i)] = v;
        }
    }

    FRAG phif[4];
#pragma unroll
    for (int nt = 0; nt < 4; ++nt)
        phif[nt].v = *(const uint4v*)&sh[ridx(wv * 64 + nt * 16 + ln, quad)];

    f32x4 pvacc[4][2];
#pragma unroll
    for (int mt = 0; mt < 4; ++mt) {
        pvacc[mt][0] = (f32x4){0.f, 0.f, 0.f, 0.f};
        pvacc[mt][1] = (f32x4){0.f, 0.f, 0.f, 0.f};
    }
    float T = 1.0f;

#pragma unroll 1
    for (int cc = 0; cc < CPS; ++cc) {
        const int c = wv * CPS + cc;   // this wave's global chunk id

        // ---- hoist all 4 VMEM frag loads; issued back-to-back, one vmcnt
        // window. pa0 consumed ~now, pa1 after m0-phase, bf after T-chain.
        FRAG pa0, pa1, bf0, bf1;
        pa0.v = ((const uint4v*)(psi + (2 * c + 0) * 256))[lane];
        pa1.v = ((const uint4v*)(psi + (2 * c + 1) * 256))[lane];
        bf0.v = ((const uint4v*)(ftg + c * 512 + 0))[lane];
        bf1.v = ((const uint4v*)(ftg + c * 512 + 256))[lane];

        // ---- Q GEMM + exp2, m-tile at a time (caps live MFMA results)
#pragma unroll
        for (int m = 0; m < 2; ++m) {
            const FRAG& pa = m ? pa1 : pa0;
            f32x4 qa[4];
#pragma unroll
            for (int nt = 0; nt < 4; ++nt)
                qa[nt] = __builtin_amdgcn_mfma_f32_16x16x32_f16(
                    pa.h, phif[nt].h, (f32x4){0.f, 0.f, 0.f, 0.f}, 0, 0, 0);
#pragma unroll
            for (int nt = 0; nt < 4; ++nt) {
                float a0 = __builtin_amdgcn_exp2f(qa[nt][0]);
                float a1 = __builtin_amdgcn_exp2f(qa[nt][1]);
                float a2 = __builtin_amdgcn_exp2f(qa[nt][2]);
                float a3 = __builtin_amdgcn_exp2f(qa[nt][3]);
                const int row = wv * 64 + nt * 16 + ln;
                const int dbase = row * 16 + ((m * 8 + quad * 2) ^ (4 * (row & 3)));
                *(uint2v*)&sh[dbase] = (uint2v){pkrtz(a0, a1), pkrtz(a2, a3)};
            }
        }

        // ---- T-chain, quad-factored (R10-verified): cumulative (1-a)
        // products off the T dependency; only T *= p is serial.
#pragma unroll
        for (int i = 0; i < 4; ++i) {
            uint4v a4 = *(const uint4v*)&sh[ridx(tid, i)];
            uint4v w4;
#pragma unroll
            for (int h = 0; h < 2; ++h) {
                H2U u0; u0.u = a4[2 * h + 0];
                H2U u1; u1.u = a4[2 * h + 1];
                float a0 = (float)u0.h[0];
                float a1 = (float)u0.h[1];
                float a2 = (float)u1.h[0];
                float a3 = (float)u1.h[1];
                float c1 = 1.0f - a0;
                float t1 = c1 * a1; float c2 = c1 - t1;
                float t2 = c2 * a2; float c3 = c2 - t2;
                float t3 = c3 * a3; float pq = c3 - t3;
                float w0 = T * a0;
                float w1 = T * t1;
                float w2 = T * t2;
                float w3 = T * t3;
                T = T * pq;
                w4[2 * h + 0] = pkrtz(w0, w1);
                w4[2 * h + 1] = pkrtz(w2, w3);
            }
            *(uint4v*)&sh[ridx(tid, i)] = w4;
        }

        // ---- PV GEMM (R6+-verified path)
#pragma unroll
        for (int mt = 0; mt < 4; ++mt) {
            FRAG af;
            af.v = *(const uint4v*)&sh[ridx(wv * 64 + mt * 16 + ln, quad)];
            pvacc[mt][0] = __builtin_amdgcn_mfma_f32_16x16x32_f16(af.h, bf0.h, pvacc[mt][0], 0, 0, 0);
            pvacc[mt][1] = __builtin_amdgcn_mfma_f32_16x16x32_f16(af.h, bf1.h, pvacc[mt][1], 0, 0, 0);
        }
    }

    // ---- write segment partials (f16 feature-pairs) into own rows; dword d
    // of row p holds features (d, d+16). |acc| <= max|feat| since sum(w)<=1.
    tT[wv][lane] = T;
#pragma unroll
    for (int mt = 0; mt < 4; ++mt)
#pragma unroll
        for (int r = 0; r < 4; ++r)
            sh[(wv * 64 + mt * 16 + quad * 4 + r) * 16 + ln] =
                pkrtz(pvacc[mt][0][r], pvacc[mt][1][r]);

    __syncthreads();

    // ---- compose segments: out = sum_s (prod_{s'<s} T_s') * acc_s
    {
        const int pp = tid >> 2;        // point 0..63
        const int g  = tid & 3;         // dword group (4 dwords)
        float t0 = tT[0][pp], t1 = tT[1][pp], t2 = tT[2][pp];
        float w1 = t0, w2 = t0 * t1, w3 = w2 * t2;

        float o[8];
        uint4v v0 = *(const uint4v*)&sh[(0 * 64 + pp) * 16 + g * 4];
#pragma unroll
        for (int j = 0; j < 4; ++j) {
            H2U u; u.u = v0[j];
            o[j] = (float)u.h[0]; o[4 + j] = (float)u.h[1];
        }
        uint4v v1 = *(const uint4v*)&sh[(1 * 64 + pp) * 16 + g * 4];
#pragma unroll
        for (int j = 0; j < 4; ++j) {
            H2U u; u.u = v1[j];
            o[j] = fmaf(w1, (float)u.h[0], o[j]);
            o[4 + j] = fmaf(w1, (float)u.h[1], o[4 + j]);
        }
        uint4v v2 = *(const uint4v*)&sh[(2 * 64 + pp) * 16 + g * 4];
#pragma unroll
        for (int j = 0; j < 4; ++j) {
            H2U u; u.u = v2[j];
            o[j] = fmaf(w2, (float)u.h[0], o[j]);
            o[4 + j] = fmaf(w2, (float)u.h[1], o[4 + j]);
        }
        uint4v v3 = *(const uint4v*)&sh[(3 * 64 + pp) * 16 + g * 4];
#pragma unroll
        for (int j = 0; j < 4; ++j) {
            H2U u; u.u = v3[j];
            o[j] = fmaf(w3, (float)u.h[0], o[j]);
            o[4 + j] = fmaf(w3, (float)u.h[1], o[4 + j]);
        }

        float* __restrict__ ob = out + (blockIdx.x * PTS + pp) * NF + g * 4;
        *(float4*)ob        = make_float4(o[0], o[1], o[2], o[3]);
        *(float4*)(ob + 16) = make_float4(o[4], o[5], o[6], o[7]);
    }
}

extern "C" void kernel_launch(void* const* d_in, const int* in_sizes, int n_in,
                              void* d_out, int out_size, void* d_ws, size_t ws_size,
                              hipStream_t stream)
{
    const float* means  = (const float*)d_in[0];   // (512,3)
    const float* scales = (const float*)d_in[1];   // (512,3)
    const float* rots   = (const float*)d_in[2];   // (512,4)
    const float* opac   = (const float*)d_in[3];   // (512,1)
    const float* feats  = (const float*)d_in[4];   // (512,32)
    const float* cam    = (const float*)d_in[5];   // (4,4)
    const float* coords = (const float*)d_in[6];   // (96,96,16,3)
    float* out = (float*)d_out;                    // (96,96,16,32) fp32

    unsigned* psi = (unsigned*)d_ws;               // 32 KiB: gaussian A-frag image
    unsigned* ftg = psi + 32 * 256;                // 32 KiB: feats B-frag image

    gr_pack<<<34, 256, 0, stream>>>(means, scales, rots, opac, cam, feats, psi, ftg);
    gr_render<<<NP / PTS, TPB, 0, stream>>>(psi, ftg, coords, out);
}